// Round 8
// baseline (253.290 us; speedup 1.0000x reference)
//
#include <hip/hip_runtime.h>
#include <math.h>

// Problem constants (B, N, TF, DM) = (16, 4096, 512, 1024)
#define B_DIM 16
#define N_SEQ 4096
#define TF_DIM 512
#define DM_DIM 1024
#define CHUNK 128
#define NCHUNK (N_SEQ / CHUNK)   // 32
#define NKT (DM_DIM / 32)        // 32 K-steps of BK=32

typedef __attribute__((ext_vector_type(4))) float f32x4;
typedef __attribute__((ext_vector_type(8))) short bf16x8;
typedef unsigned short u16;
typedef unsigned int u32;

__device__ __forceinline__ u16 f2bf(float f) {
    u32 u = __builtin_bit_cast(u32, f);
    u += 0x7fffu + ((u >> 16) & 1u);
    return (u16)(u >> 16);
}

__device__ __forceinline__ u32 cvtpk(float lo, float hi) {
    u32 r;
    asm("v_cvt_pk_bf16_f32 %0, %1, %2" : "=v"(r) : "v"(lo), "v"(hi));
    return r;
}

// async global->LDS DMA, 16B/lane; LDS dest is WAVE-UNIFORM base (+lane*16B
// implicit); global source is per-lane (swizzle lives in the source address).
__device__ __forceinline__ void gload16(const u16* g, u16* l) {
    __builtin_amdgcn_global_load_lds(
        (const __attribute__((address_space(1))) void*)g,
        (__attribute__((address_space(3))) void*)l, 16, 0, 0);
}

// Drain MY staged gloads (issued before COMPUTE, so latency is hidden under
// the MFMA phase), then barrier. ds_reads are already consumed by MFMA issue.
#define SYNC_DRAIN() asm volatile("s_waitcnt vmcnt(0)\n\ts_barrier" ::: "memory")

// ---------------------------------------------------------------------------
// K0: fp32 -> bf16 pre-convert of latent_seasonal (32 MB out) and w_seasonal
// (1 MB out), so the GEMM stages bf16 via global_load_lds with no VALU pack.
// ---------------------------------------------------------------------------
__global__ __launch_bounds__(256)
void cvt_bf16(const float* __restrict__ ls, const float* __restrict__ wm,
              u16* __restrict__ lsb, u16* __restrict__ wmb)
{
    const size_t LSG = (size_t)B_DIM * N_SEQ * DM_DIM / 4;  // 4194304 granules
    const size_t i = (size_t)blockIdx.x * 256 + threadIdx.x;
    const float* src;
    u16* dst;
    if (i < LSG) { src = ls + i * 4; dst = lsb + i * 4; }
    else         { const size_t j = i - LSG; src = wm + j * 4; dst = wmb + j * 4; }
    const f32x4 v = *(const f32x4*)src;
    u32* d = (u32*)dst;
    d[0] = cvtpk(v[0], v[1]);
    d[1] = cvtpk(v[2], v[3]);
}

// ---------------------------------------------------------------------------
// K1: u[m,f] = 2*x[m,f] - ( ls[m,:] . w[f,:] + bias[f] ),  m = b*N + n
// plus fused chunk-end EMA:  e[rowPanel, f] = sum_j a*c^(127-j)*u[row0+j, f]
//
// m97-proven structure: 128x128 tile, BK=32 bf16, 4 waves (2x2),
// mfma_f32_16x16x32_bf16, global_load_lds(16B) double-buffered staging,
// 2-phase loop with vmcnt(0) drained AFTER compute (T3 recipe).
// LDS swizzle (rule #21): gload dest linear; SOURCE pre-swizzled per lane
// with the inverse of  granule' = (row*4+slot) ^ (row&7)  ; ds_read applies
// the same XOR -> 2-way bank aliasing only (free).
// XCD remap: 4 f-siblings of one A-row-panel consecutive on one XCD.
// ---------------------------------------------------------------------------
__global__ __launch_bounds__(256, 2)
void gemm_u_kernel(const float* __restrict__ x,
                   const u16* __restrict__ lsb,
                   const u16* __restrict__ wmb,
                   const float* __restrict__ bias,
                   const float* __restrict__ alpha,
                   u16* __restrict__ u,
                   float* __restrict__ e)
{
    __shared__ u16 As[2][4096];     // 128 rows x 32 k bf16, swizzled
    __shared__ u16 Ws[2][4096];
    __shared__ float red[2][4][16]; // cross-wave e-reduction

    const int tid = threadIdx.x;

    // XCD-aware decode of the dispatch slot
    const int s  = blockIdx.x;                   // 0..2047, xcd ~ s&7
    const int kk = s >> 3;
    const int fb = kk & 3;                       // f-block 0..3
    const int rp = (s & 7) + ((kk >> 2) << 3);   // row-panel 0..511
    const int f0   = fb * 128;
    const int row0 = rp * 128;

    const int lane = tid & 63;
    const int wid  = tid >> 6;
    const int wm = wid >> 1, wn = wid & 1;
    const int l15 = lane & 15, l4 = lane >> 4;

    // --- staging source decode: linear dest granule G (16B units) receives
    // data of (row,slot) where (row*4+slot)^(row&7) == G. Inverse:
    //   row = (G>>2) with bit0 replaced by (G>>2 ^ G>>4)&1
    //   slot = (G&3) ^ (row&3)
    const int G0 = wid * 128 + lane;   // issue 0 granule
    const int G1 = G0 + 64;            // issue 1 granule
    int row_a, slot_a, row_b, slot_b;
    { const int r = G0 >> 2;
      row_a  = (r & ~1) | ((r ^ (G0 >> 4)) & 1);
      slot_a = (G0 & 3) ^ (row_a & 3); }
    { const int r = G1 >> 2;
      row_b  = (r & ~1) | ((r ^ (G1 >> 4)) & 1);
      slot_b = (G1 & 3) ^ (row_b & 3); }

    const u16* aSrc0 = lsb + (size_t)(row0 + row_a) * DM_DIM + slot_a * 8;
    const u16* aSrc1 = lsb + (size_t)(row0 + row_b) * DM_DIM + slot_b * 8;
    const u16* wSrc0 = wmb + (size_t)(f0 + row_a) * DM_DIM + slot_a * 8;
    const u16* wSrc1 = wmb + (size_t)(f0 + row_b) * DM_DIM + slot_b * 8;

#define STAGE(BUF, KT) do {                                              \
        const int _o = (KT) * 32;                                        \
        gload16(aSrc0 + _o, &As[BUF][wid * 1024]);                       \
        gload16(aSrc1 + _o, &As[BUF][wid * 1024 + 512]);                 \
        gload16(wSrc0 + _o, &Ws[BUF][wid * 1024]);                       \
        gload16(wSrc1 + _o, &Ws[BUF][wid * 1024 + 512]);                 \
    } while (0)

    // --- fragment read offsets (ushort units), same XOR swizzle
    int rofa[4], rofw[4];
    const int rxor = (l15 & 7) << 3;
#pragma unroll
    for (int i = 0; i < 4; ++i) {
        rofa[i] = ((wm * 64 + i * 16 + l15) * 32 + l4 * 8) ^ rxor;
        rofw[i] = ((wn * 64 + i * 16 + l15) * 32 + l4 * 8) ^ rxor;
    }

    f32x4 acc[4][4];
#pragma unroll
    for (int i = 0; i < 4; ++i)
#pragma unroll
        for (int j = 0; j < 4; ++j) acc[i][j] = (f32x4){0.f, 0.f, 0.f, 0.f};

#define COMPUTE(BUF) do {                                                \
        const u16* _Ab = As[BUF];                                        \
        const u16* _Wb = Ws[BUF];                                        \
        bf16x8 _af[4], _wf[4];                                           \
        _Pragma("unroll")                                                \
        for (int i = 0; i < 4; ++i) {                                    \
            _af[i] = *(const bf16x8*)(_Ab + rofa[i]);                    \
            _wf[i] = *(const bf16x8*)(_Wb + rofw[i]);                    \
        }                                                                \
        _Pragma("unroll")                                                \
        for (int mi = 0; mi < 4; ++mi)                                   \
        _Pragma("unroll")                                                \
        for (int ni = 0; ni < 4; ++ni)                                   \
            acc[mi][ni] = __builtin_amdgcn_mfma_f32_16x16x32_bf16(       \
                _af[mi], _wf[ni], acc[mi][ni], 0, 0, 0);                 \
    } while (0)

    // prologue
    STAGE(0, 0);
    SYNC_DRAIN();

#pragma unroll 1
    for (int kt = 0; kt < NKT; kt += 2) {
        // phase kt: issue DMA for tile kt+1 -> buf1 (hidden under MFMAs),
        // compute buf0, then drain+barrier (loads had a full phase).
        if (kt + 1 < NKT) STAGE(1, kt + 1);
        COMPUTE(0);
        SYNC_DRAIN();

        if (kt + 2 < NKT) STAGE(0, kt + 2);
        COMPUTE(1);
        SYNC_DRAIN();
    }

    // epilogue: u = 2x - (acc + bias) (stored bf16); fused chunk-end EMA
    const float a = 1.0f / (1.0f + expf(-alpha[0]));
    const float c = 1.0f - a;
    const float l2c = log2f(c);

    float bia[4];
#pragma unroll
    for (int ni = 0; ni < 4; ++ni) bia[ni] = bias[f0 + wn * 64 + ni * 16 + l15];

    float epart[4] = {0.f, 0.f, 0.f, 0.f};

#pragma unroll
    for (int mi = 0; mi < 4; ++mi) {
#pragma unroll
        for (int j = 0; j < 4; ++j) {
            const int r = wm * 64 + mi * 16 + l4 * 4 + j;   // row in chunk
            const size_t rb = (size_t)(row0 + r) * TF_DIM;
            const float wgt = (r == CHUNK - 1)
                                  ? a
                                  : a * exp2f((float)(CHUNK - 1 - r) * l2c);
#pragma unroll
            for (int ni = 0; ni < 4; ++ni) {
                const int f = f0 + wn * 64 + ni * 16 + l15;
                const float uval = 2.0f * x[rb + f] - (acc[mi][ni][j] + bia[ni]);
                u[rb + f] = f2bf(uval);
                epart[ni] = fmaf(wgt, uval, epart[ni]);
            }
        }
    }

    // reduce over l4 (shuffle) then over wm (LDS)
#pragma unroll
    for (int ni = 0; ni < 4; ++ni) {
        epart[ni] += __shfl_xor(epart[ni], 16, 64);
        epart[ni] += __shfl_xor(epart[ni], 32, 64);
    }
    if (wm == 1 && l4 == 0) {
#pragma unroll
        for (int ni = 0; ni < 4; ++ni) red[wn][ni][l15] = epart[ni];
    }
    __syncthreads();
    if (wm == 0 && l4 == 0) {
#pragma unroll
        for (int ni = 0; ni < 4; ++ni) {
            const int f = f0 + wn * 64 + ni * 16 + l15;
            e[(size_t)rp * TF_DIM + f] = epart[ni] + red[wn][ni][l15];
        }
    }
}

// ---------------------------------------------------------------------------
// K3: serial carry scan over chunks per (b,f)
// ---------------------------------------------------------------------------
__global__ __launch_bounds__(256)
void ema_carry(const float* __restrict__ e, const float* __restrict__ alpha,
               float* __restrict__ carry)
{
    const int idx = blockIdx.x * 256 + threadIdx.x;  // b*TF + f
    const int f = idx & (TF_DIM - 1);
    const int b = idx >> 9;
    const float a = 1.0f / (1.0f + expf(-alpha[0]));
    const float c = 1.0f - a;
    const float cC = exp2f((float)CHUNK * log2f(c));  // c^CHUNK
    const size_t base = (size_t)b * NCHUNK * TF_DIM + f;
    float Y = 0.0f;
    carry[base] = 0.0f;
    for (int ch = 1; ch < NCHUNK; ++ch) {
        Y = fmaf(cC, Y, e[base + (size_t)(ch - 1) * TF_DIM]);
        carry[base + (size_t)ch * TF_DIM] = Y;
    }
}

// ---------------------------------------------------------------------------
// K4: apply chunk-local EMA with carry-in. u is bf16; each thread owns two
// adjacent f columns (uint load = 2 bf16, float2 store).
// ---------------------------------------------------------------------------
__global__ __launch_bounds__(256)
void ema_apply(const u16* __restrict__ u, const float* __restrict__ carry,
               const float* __restrict__ alpha, float* __restrict__ out)
{
    const int bc = blockIdx.x;                 // b*NCHUNK + ch, 0..511
    const int tid = threadIdx.x;               // owns f = 2*tid, 2*tid+1
    const float a = 1.0f / (1.0f + expf(-alpha[0]));
    const float c = 1.0f - a;
    float y0 = carry[(size_t)bc * TF_DIM + 2 * tid];
    float y1 = carry[(size_t)bc * TF_DIM + 2 * tid + 1];
    const u32* up = (const u32*)(u + (size_t)bc * CHUNK * TF_DIM) + tid;
    float2*    op = (float2*)(out + (size_t)bc * CHUNK * TF_DIM) + tid;
#pragma unroll 4
    for (int j = 0; j < CHUNK; ++j) {
        const u32 w = up[(size_t)j * (TF_DIM / 2)];
        const float u0 = __builtin_bit_cast(float, (w & 0xffffu) << 16);
        const float u1 = __builtin_bit_cast(float, (w >> 16) << 16);
        y0 = fmaf(c, y0, a * u0);
        y1 = fmaf(c, y1, a * u1);
        op[(size_t)j * (TF_DIM / 2)] = make_float2(y0, y1);
    }
}

extern "C" void kernel_launch(void* const* d_in, const int* in_sizes, int n_in,
                              void* d_out, int out_size, void* d_ws, size_t ws_size,
                              hipStream_t stream) {
    // setup_inputs order: x, latent_growth, latent_seasonal, alpha,
    //                     w_growth, b_growth, w_seasonal, b_seasonal
    const float* x     = (const float*)d_in[0];
    const float* ls    = (const float*)d_in[2];
    const float* alpha = (const float*)d_in[3];
    const float* wmat  = (const float*)d_in[6];
    const float* bias  = (const float*)d_in[7];
    float* out = (float*)d_out;

    // workspace layout (all 16B-aligned)
    u16*   u     = (u16*)d_ws;                                 // 67 MB (bf16 u)
    u16*   lsb   = u + (size_t)B_DIM * N_SEQ * TF_DIM;         // 32 MB bf16 ls
    u16*   wmb   = lsb + (size_t)B_DIM * N_SEQ * DM_DIM;       // 1 MB bf16 w
    float* e     = (float*)(wmb + (size_t)TF_DIM * DM_DIM);    // 1 MB
    float* carry = e + (size_t)B_DIM * NCHUNK * TF_DIM;        // 1 MB

    // K0: fp32 -> bf16 conversion of ls + wmat
    const int cvt_blocks = (B_DIM * N_SEQ * DM_DIM / 4 + TF_DIM * DM_DIM / 4) / 256;
    cvt_bf16<<<cvt_blocks, 256, 0, stream>>>(ls, wmat, lsb, wmb);

    // K1: GEMM + u + chunk-end EMA
    gemm_u_kernel<<<2048, 256, 0, stream>>>(x, lsb, wmb, bias, alpha, u, e);

    ema_carry<<<(B_DIM * TF_DIM) / 256, 256, 0, stream>>>(e, alpha, carry);
    ema_apply<<<B_DIM * NCHUNK, 256, 0, stream>>>(u, carry, alpha, out);
}

// Round 9
// 244.418 us; speedup vs baseline: 1.0363x; 1.0363x over previous
//
#include <hip/hip_runtime.h>
#include <math.h>

// Problem constants (B, N, TF, DM) = (16, 4096, 512, 1024)
#define B_DIM 16
#define N_SEQ 4096
#define TF_DIM 512
#define DM_DIM 1024
#define CHUNK 128
#define NCHUNK (N_SEQ / CHUNK)   // 32
#define NKT (DM_DIM / 32)        // 32 K-phases of BK=32

typedef __attribute__((ext_vector_type(4))) float f32x4;
typedef __attribute__((ext_vector_type(8))) short bf16x8;
typedef unsigned short u16;
typedef unsigned int u32;

__device__ __forceinline__ u16 f2bf(float f) {
    u32 u = __builtin_bit_cast(u32, f);
    u += 0x7fffu + ((u >> 16) & 1u);
    return (u16)(u >> 16);
}

__device__ __forceinline__ u32 cvtpk(float lo, float hi) {
    u32 r;
    asm("v_cvt_pk_bf16_f32 %0, %1, %2" : "=v"(r) : "v"(lo), "v"(hi));
    return r;
}

// async global->LDS DMA, 16B/lane; LDS dest is WAVE-UNIFORM base (+lane*16B
// implicit); global source is per-lane (swizzle lives in the source address).
__device__ __forceinline__ void gload16(const u16* g, u16* l) {
    __builtin_amdgcn_global_load_lds(
        (const __attribute__((address_space(1))) void*)g,
        (__attribute__((address_space(3))) void*)l, 16, 0, 0);
}

// Drain staged gloads (issued BEFORE compute, so latency hides under MFMAs),
// then barrier.
#define SYNC_DRAIN() asm volatile("s_waitcnt vmcnt(0)\n\ts_barrier" ::: "memory")

// ---------------------------------------------------------------------------
// K0: fp32 -> bf16 pre-convert of latent_seasonal (134->67 MB) and w_seasonal
// (2->1 MB) so the GEMM stages bf16 via global_load_lds with no VALU pack.
// ---------------------------------------------------------------------------
__global__ __launch_bounds__(256)
void cvt_bf16(const float* __restrict__ ls, const float* __restrict__ wm,
              u16* __restrict__ lsb, u16* __restrict__ wmb)
{
    const size_t LSG = (size_t)B_DIM * N_SEQ * DM_DIM / 4;  // 4-elem granules
    const size_t i = (size_t)blockIdx.x * 256 + threadIdx.x;
    const float* src;
    u16* dst;
    if (i < LSG) { src = ls + i * 4; dst = lsb + i * 4; }
    else         { const size_t j = i - LSG; src = wm + j * 4; dst = wmb + j * 4; }
    const f32x4 v = *(const f32x4*)src;
    u32* d = (u32*)dst;
    d[0] = cvtpk(v[0], v[1]);
    d[1] = cvtpk(v[2], v[3]);
}

// ---------------------------------------------------------------------------
// K1: u[m,f] = 2*x[m,f] - ( ls[m,:] . w[f,:] + bias[f] ),  m = b*N + n
// plus fused chunk-end EMA per 128-row chunk (2 chunks per block).
//
// BM=256 x BN=128, BK=32, 512 threads / 8 waves (4 M x 2 N),
// mfma_f32_16x16x32_bf16. HALVED machine phase count vs 128x128 (the
// ~4000cy/phase overhead measured in rounds 5-8 is structure-invariant;
// amortize it). global_load_lds staging, 16 rows x 64B contiguous per
// instruction (granule-permuted within 64B segments -> swizzled + fully
// coalesced). 2-phase loop, vmcnt(0) drained AFTER compute.
// XCD remap: 4 f-siblings of one 512KB A-panel consecutive on one XCD.
// ---------------------------------------------------------------------------
__global__ __launch_bounds__(512, 4)
void gemm_u_kernel(const float* __restrict__ x,
                   const u16* __restrict__ lsb,
                   const u16* __restrict__ wmb,
                   const float* __restrict__ bias,
                   const float* __restrict__ alpha,
                   u16* __restrict__ u,
                   float* __restrict__ e)
{
    __shared__ u16 As[2][8192];     // 256 rows x 32 k bf16, swizzled (16KB ea)
    __shared__ u16 Ws[2][4096];     // 128 rows x 32 k bf16 (8KB ea)
    __shared__ float red[2][2][4][16]; // cross-wave e-reduction (2 chunks)

    const int tid = threadIdx.x;

    // XCD-aware decode: s&7 = xcd slot; 4 f-siblings consecutive per XCD.
    const int s  = blockIdx.x;                   // 0..1023
    const int kk = s >> 3;                       // 0..127
    const int fb = kk & 3;                       // f-block 0..3
    const int rp = (s & 7) + ((kk >> 2) << 3);   // row-panel 0..255
    const int f0   = fb * 128;
    const int row0 = rp * 256;

    const int lane = tid & 63;
    const int wid  = tid >> 6;                   // 0..7
    const int wm = wid >> 1, wn = wid & 1;       // wave grid 4 x 2
    const int l15 = lane & 15, l4 = lane >> 4;

    // --- staging: instr covers 16 rows x 64B (4 granules/row, permuted):
    // lane -> row base + (lane>>2), source granule gc = (lane&3) ^ (row&3).
    const int srow = lane >> 2;                  // 0..15
    const int sgc  = (lane & 3) ^ (srow & 3);    // swizzled source granule
    const u16* pA = lsb + (size_t)(row0 + wid * 32 + srow) * DM_DIM + sgc * 8;
    const u16* pW = wmb + (size_t)(f0 + wid * 16 + srow) * DM_DIM + sgc * 8;

#define STAGE(BUF, KT) do {                                              \
        const int _o = (KT) * 32;                                        \
        gload16(pA + _o,                 &As[BUF][wid * 1024]);          \
        gload16(pA + _o + 16 * DM_DIM,   &As[BUF][wid * 1024 + 512]);    \
        gload16(pW + _o,                 &Ws[BUF][wid * 512]);           \
    } while (0)

    // --- fragment read offsets (u16 units): row*32 + ((l4 ^ (row&3))*8)
    int rofa[4], rofw[4];
#pragma unroll
    for (int i = 0; i < 4; ++i) {
        const int ra = wm * 64 + i * 16 + l15;
        const int rw = wn * 64 + i * 16 + l15;
        rofa[i] = ra * 32 + ((l4 ^ (ra & 3)) * 8);
        rofw[i] = rw * 32 + ((l4 ^ (rw & 3)) * 8);
    }

    f32x4 acc[4][4];
#pragma unroll
    for (int i = 0; i < 4; ++i)
#pragma unroll
        for (int j = 0; j < 4; ++j) acc[i][j] = (f32x4){0.f, 0.f, 0.f, 0.f};

#define COMPUTE(BUF) do {                                                \
        const u16* _Ab = As[BUF];                                        \
        const u16* _Wb = Ws[BUF];                                        \
        bf16x8 _af[4], _wf[4];                                           \
        _Pragma("unroll")                                                \
        for (int i = 0; i < 4; ++i) {                                    \
            _af[i] = *(const bf16x8*)(_Ab + rofa[i]);                    \
            _wf[i] = *(const bf16x8*)(_Wb + rofw[i]);                    \
        }                                                                \
        _Pragma("unroll")                                                \
        for (int mi = 0; mi < 4; ++mi)                                   \
        _Pragma("unroll")                                                \
        for (int ni = 0; ni < 4; ++ni)                                   \
            acc[mi][ni] = __builtin_amdgcn_mfma_f32_16x16x32_bf16(       \
                _af[mi], _wf[ni], acc[mi][ni], 0, 0, 0);                 \
    } while (0)

    // prologue
    STAGE(0, 0);
    SYNC_DRAIN();

#pragma unroll 1
    for (int kt = 0; kt < NKT; kt += 2) {
        if (kt + 1 < NKT) STAGE(1, kt + 1);   // DMA hides under MFMAs
        COMPUTE(0);
        SYNC_DRAIN();

        if (kt + 2 < NKT) STAGE(0, kt + 2);
        COMPUTE(1);
        SYNC_DRAIN();
    }

    // epilogue: u = 2x - (acc + bias) (stored bf16); fused chunk-end EMA.
    // Each thread's rows live in one 128-chunk: chunk-in-block = wm>>1.
    const float a = 1.0f / (1.0f + expf(-alpha[0]));
    const float c = 1.0f - a;
    const float l2c = log2f(c);

    float bia[4];
#pragma unroll
    for (int ni = 0; ni < 4; ++ni) bia[ni] = bias[f0 + wn * 64 + ni * 16 + l15];

    float epart[4] = {0.f, 0.f, 0.f, 0.f};

#pragma unroll
    for (int mi = 0; mi < 4; ++mi) {
#pragma unroll
        for (int j = 0; j < 4; ++j) {
            const int r = wm * 64 + mi * 16 + l4 * 4 + j;   // row in block 0..255
            const int rc = r & (CHUNK - 1);                 // row in chunk
            const size_t rb = (size_t)(row0 + r) * TF_DIM;
            const float wgt = (rc == CHUNK - 1)
                                  ? a
                                  : a * exp2f((float)(CHUNK - 1 - rc) * l2c);
#pragma unroll
            for (int ni = 0; ni < 4; ++ni) {
                const int f = f0 + wn * 64 + ni * 16 + l15;
                const float uval = 2.0f * x[rb + f] - (acc[mi][ni][j] + bia[ni]);
                u[rb + f] = f2bf(uval);
                epart[ni] = fmaf(wgt, uval, epart[ni]);
            }
        }
    }

    // reduce over l4 (shuffle), then over the wm-pair of each chunk (LDS)
#pragma unroll
    for (int ni = 0; ni < 4; ++ni) {
        epart[ni] += __shfl_xor(epart[ni], 16, 64);
        epart[ni] += __shfl_xor(epart[ni], 32, 64);
    }
    const int ch = wm >> 1;           // chunk-in-block 0..1
    if ((wm & 1) == 1 && l4 == 0) {   // odd wm of each pair publishes
#pragma unroll
        for (int ni = 0; ni < 4; ++ni) red[ch][wn][ni][l15] = epart[ni];
    }
    __syncthreads();
    if ((wm & 1) == 0 && l4 == 0) {
#pragma unroll
        for (int ni = 0; ni < 4; ++ni) {
            const int f = f0 + wn * 64 + ni * 16 + l15;
            e[(size_t)(rp * 2 + ch) * TF_DIM + f] = epart[ni] + red[ch][wn][ni][l15];
        }
    }
}

// ---------------------------------------------------------------------------
// K3: serial carry scan over chunks per (b,f)
// ---------------------------------------------------------------------------
__global__ __launch_bounds__(256)
void ema_carry(const float* __restrict__ e, const float* __restrict__ alpha,
               float* __restrict__ carry)
{
    const int idx = blockIdx.x * 256 + threadIdx.x;  // b*TF + f
    const int f = idx & (TF_DIM - 1);
    const int b = idx >> 9;
    const float a = 1.0f / (1.0f + expf(-alpha[0]));
    const float c = 1.0f - a;
    const float cC = exp2f((float)CHUNK * log2f(c));  // c^CHUNK
    const size_t base = (size_t)b * NCHUNK * TF_DIM + f;
    float Y = 0.0f;
    carry[base] = 0.0f;
    for (int ch = 1; ch < NCHUNK; ++ch) {
        Y = fmaf(cC, Y, e[base + (size_t)(ch - 1) * TF_DIM]);
        carry[base + (size_t)ch * TF_DIM] = Y;
    }
}

// ---------------------------------------------------------------------------
// K4: apply chunk-local EMA with carry-in. u is bf16; each thread owns two
// adjacent f columns (uint load = 2 bf16, float2 store).
// ---------------------------------------------------------------------------
__global__ __launch_bounds__(256)
void ema_apply(const u16* __restrict__ u, const float* __restrict__ carry,
               const float* __restrict__ alpha, float* __restrict__ out)
{
    const int bc = blockIdx.x;                 // b*NCHUNK + ch, 0..511
    const int tid = threadIdx.x;               // owns f = 2*tid, 2*tid+1
    const float a = 1.0f / (1.0f + expf(-alpha[0]));
    const float c = 1.0f - a;
    float y0 = carry[(size_t)bc * TF_DIM + 2 * tid];
    float y1 = carry[(size_t)bc * TF_DIM + 2 * tid + 1];
    const u32* up = (const u32*)(u + (size_t)bc * CHUNK * TF_DIM) + tid;
    float2*    op = (float2*)(out + (size_t)bc * CHUNK * TF_DIM) + tid;
#pragma unroll 4
    for (int j = 0; j < CHUNK; ++j) {
        const u32 w = up[(size_t)j * (TF_DIM / 2)];
        const float u0 = __builtin_bit_cast(float, (w & 0xffffu) << 16);
        const float u1 = __builtin_bit_cast(float, (w >> 16) << 16);
        y0 = fmaf(c, y0, a * u0);
        y1 = fmaf(c, y1, a * u1);
        op[(size_t)j * (TF_DIM / 2)] = make_float2(y0, y1);
    }
}

extern "C" void kernel_launch(void* const* d_in, const int* in_sizes, int n_in,
                              void* d_out, int out_size, void* d_ws, size_t ws_size,
                              hipStream_t stream) {
    // setup_inputs order: x, latent_growth, latent_seasonal, alpha,
    //                     w_growth, b_growth, w_seasonal, b_seasonal
    const float* x     = (const float*)d_in[0];
    const float* ls    = (const float*)d_in[2];
    const float* alpha = (const float*)d_in[3];
    const float* wmat  = (const float*)d_in[6];
    const float* bias  = (const float*)d_in[7];
    float* out = (float*)d_out;

    // workspace layout (16B-aligned)
    u16*   u     = (u16*)d_ws;                                 // 67 MB bf16
    u16*   lsb   = u + (size_t)B_DIM * N_SEQ * TF_DIM;         // 134 MB bf16
    u16*   wmb   = lsb + (size_t)B_DIM * N_SEQ * DM_DIM;       // 1 MB bf16
    float* e     = (float*)(wmb + (size_t)TF_DIM * DM_DIM);    // 1 MB
    float* carry = e + (size_t)B_DIM * NCHUNK * TF_DIM;        // 1 MB

    // K0: fp32 -> bf16 conversion of ls + wmat
    const int cvt_blocks = (B_DIM * N_SEQ * DM_DIM / 4 + TF_DIM * DM_DIM / 4) / 256;
    cvt_bf16<<<cvt_blocks, 256, 0, stream>>>(ls, wmat, lsb, wmb);

    // K1: GEMM + u + chunk-end EMA  (1024 blocks of 512 threads)
    gemm_u_kernel<<<1024, 512, 0, stream>>>(x, lsb, wmb, bias, alpha, u, e);

    ema_carry<<<(B_DIM * TF_DIM) / 256, 256, 0, stream>>>(e, alpha, carry);
    ema_apply<<<B_DIM * NCHUNK, 256, 0, stream>>>(u, carry, alpha, out);
}